// Round 6
// baseline (283.480 us; speedup 1.0000x reference)
//
#include <hip/hip_runtime.h>
#include <hip/hip_bf16.h>

#define BB    128
#define CIN   256
#define COUT  256
#define NN    64
#define KW    5
#define DIRR  16
#define ZTOT  (BB*NN)
#define SX    264   // xs row stride (bf16): 528 B = 33*16 -> odd 16B-slot stride, A-reads conflict-free

typedef __attribute__((ext_vector_type(4))) float f32x4;
typedef __attribute__((ext_vector_type(8))) short s16x8;

__device__ inline ushort f2bf(float f) {
    __hip_bfloat16 h = __float2bfloat16(f);
    return *(const ushort*)&h;
}
__device__ inline float bf2f(ushort u) {
    union { unsigned int ui; float f; } cv; cv.ui = ((unsigned int)u) << 16;
    return cv.f;
}
__device__ inline void gload_lds16(const void* g, void* l) {
    __builtin_amdgcn_global_load_lds(
        (const __attribute__((address_space(1))) void*)g,
        (__attribute__((address_space(3))) void*)l, 16, 0, 0);
}
__device__ inline float wave_sum(float v) {
    #pragma unroll
    for (int o = 32; o > 0; o >>= 1) v += __shfl_down(v, o, 64);
    return v;
}
__device__ inline float silu(float x) { return x / (1.f + __expf(-x)); }

// ---------------------------------------------------------------------------
// K0a: pack conv weights f32 -> bf16, wb[l][k][chunk8][ SWIZZLED(c,cl) ].
// Swizzle: 16B-group g = 4c + (cl>>3); swz = g ^ ((c>>1)&7)  (bijective).
// conv reads with the same swizzle; global_load_lds copy is identity-linear.
// ---------------------------------------------------------------------------
__global__ __launch_bounds__(256) void pack_w_k(const float* __restrict__ w,
                                                ushort* __restrict__ wb)
{
    int idx = blockIdx.x * 256 + threadIdx.x;      // 1310720
    int cl = idx & 31;
    int c  = (idx >> 5) & 255;
    int ch = (idx >> 13) & 7;
    int k  = (idx >> 16) % 5;
    int l  = idx / 327680;
    int cin = ch * 32 + cl;
    int g   = (c << 2) | (cl >> 3);
    int swz = g ^ ((c >> 1) & 7);
    size_t tile = ((size_t)(l * 5 + k) * 8 + ch) * 8192;
    wb[tile + swz * 8 + (cl & 7)] =
        f2bf(w[(((size_t)(l * COUT + c) * CIN) + cin) * KW + k]);
}

// ---------------------------------------------------------------------------
// K0b: pack gw (bf16 [c][k]), tg (bf16 [p][i]), fg transposed (bf16 [i][p])
// ---------------------------------------------------------------------------
__global__ __launch_bounds__(256) void pack2_k(const float* __restrict__ gw,
                                               const float* __restrict__ tg,
                                               const float* __restrict__ fg,
                                               ushort* __restrict__ gwb,
                                               ushort* __restrict__ tgb,
                                               ushort* __restrict__ fgTb)
{
    int idx = blockIdx.x * 256 + threadIdx.x;      // 67584 total
    if (idx < 65536) {
        gwb[idx] = f2bf(gw[idx]);
    } else if (idx < 66560) {
        int j = idx - 65536;
        tgb[j] = f2bf(tg[j]);
    } else if (idx < 67584) {
        int j = idx - 66560;                        // j = p*16 + i
        int p = j >> 4, i = j & 15;
        fgTb[i * 64 + p] = f2bf(fg[j]);
    }
}

// ---------------------------------------------------------------------------
// K1: per-(b,i) conv as bf16 MFMA GEMM. M=64(n) x N=256(c), K=5 shifts x 256 cin.
// ---------------------------------------------------------------------------
__global__ __launch_bounds__(256) void conv_mfma_k(const float* __restrict__ x,
                                                   const ushort* __restrict__ wb,
                                                   const float* __restrict__ bias,
                                                   ushort* __restrict__ hbuf)
{
    __shared__ __align__(16) ushort xs[68 * SX];        // [n+2halo][cin]
    __shared__ __align__(16) ushort bs[2][COUT * 32];   // swizzled [c][cin32], dbuf

    const int tid  = threadIdx.x;
    const int lane = tid & 63;
    const int wid  = tid >> 6;
    const int blk  = blockIdx.x;
    const int b = blk >> 4, i = blk & 15;
    const int l = (i == 0) ? 0 : (i < 4) ? 1 : (i < 9) ? 2 : 3;

    // ---- stage x[b,:,i,:] transposed -> xs[2+n][cin], conflict-free writes:
    // lanes are cin-major (64 consecutive cin, same row => 128 B contiguous b16 stores)
    {
        const float4* xb = (const float4*)(x + (((size_t)b * CIN) * DIRR + i) * NN);
        #pragma unroll
        for (int p = 0; p < 16; ++p) {
            int cin = (tid & 63) | ((p & 3) << 6);      // 0..255
            int nq  = ((tid >> 6) << 2) | (p >> 2);     // 0..15 (float4 index in n)
            float4 v = xb[(size_t)cin * (DIRR * NN / 4) + nq];
            ushort* dst = xs + (size_t)(2 + nq * 4) * SX + cin;
            dst[0]      = f2bf(v.x);
            dst[SX]     = f2bf(v.y);
            dst[2 * SX] = f2bf(v.z);
            dst[3 * SX] = f2bf(v.w);
        }
        xs[ 0 * SX + tid] = 0; xs[ 1 * SX + tid] = 0;
        xs[66 * SX + tid] = 0; xs[67 * SX + tid] = 0;
    }

    const ushort* wl = wb + (size_t)l * (5 * 8 * COUT * 32);
    auto stageB = [&](int s, int ch, int buf) {
        const char* src = (const char*)(wl + (size_t)(s * 8 + ch) * COUT * 32);
        char* dst = (char*)bs[buf];
        #pragma unroll
        for (int q = 0; q < 4; ++q) {
            int d = q * 4096 + tid * 16;
            gload_lds16(src + d, dst + d);
        }
    };

    stageB(0, 0, 0);
    __syncthreads();

    f32x4 acc[4][4];
    #pragma unroll
    for (int m = 0; m < 4; ++m)
        #pragma unroll
        for (int j = 0; j < 4; ++j) acc[m][j] = (f32x4){0.f, 0.f, 0.f, 0.f};

    const int kb = lane >> 4;
    const int lr = lane & 15;

    // precompute swizzled B-read element offsets (per j)
    int boff[4];
    #pragma unroll
    for (int j = 0; j < 4; ++j) {
        int c = wid * 64 + j * 16 + lr;
        int g = (c << 2) | kb;
        boff[j] = (g ^ ((c >> 1) & 7)) * 8;
    }

    int step = 0;
    #pragma unroll 1
    for (int s = 0; s < 5; ++s) {
        #pragma unroll 1
        for (int ch = 0; ch < 8; ++ch, ++step) {
            int cur = step & 1;
            int ns  = (ch == 7) ? s + 1 : s;
            int nch = (ch == 7) ? 0 : ch + 1;
            if (ns < 5) stageB(ns, nch, cur ^ 1);

            int cin0 = ch * 32;
            s16x8 av[4], bv[4];
            #pragma unroll
            for (int m = 0; m < 4; ++m) {
                int r = m * 16 + lr + s;
                av[m] = *(const s16x8*)(xs + (size_t)r * SX + cin0 + kb * 8);
            }
            #pragma unroll
            for (int j = 0; j < 4; ++j)
                bv[j] = *(const s16x8*)(bs[cur] + boff[j]);
            #pragma unroll
            for (int m = 0; m < 4; ++m)
                #pragma unroll
                for (int j = 0; j < 4; ++j)
                    acc[m][j] = __builtin_amdgcn_mfma_f32_16x16x32_bf16(av[m], bv[j], acc[m][j], 0, 0, 0);
            __syncthreads();
        }
    }

    // ---- epilogue: bias (i==0) + bf16 store. D: col=lane&15, row=(lane>>4)*4+r
    const int row0 = (lane >> 4) * 4;
    #pragma unroll
    for (int j = 0; j < 4; ++j) {
        int c = wid * 64 + j * 16 + lr;
        float bvv = (i == 0) ? bias[c] : 0.f;
        #pragma unroll
        for (int m = 0; m < 4; ++m)
            #pragma unroll
            for (int r = 0; r < 4; ++r) {
                int n = m * 16 + row0 + r;
                size_t z = (size_t)b * NN + n;
                hbuf[(z * DIRR + i) * COUT + c] = f2bf(acc[m][j][r] + bvv);
            }
    }
}

// ---------------------------------------------------------------------------
// K2a: norm per z (block = 2 z). Writes hn2[c][z][i] bf16 + hn0[z][c] bf16.
// ---------------------------------------------------------------------------
__global__ __launch_bounds__(256) void norm_k(const ushort* __restrict__ hbuf,
                                              const float* __restrict__ afw,
                                              ushort* __restrict__ hn2,
                                              ushort* __restrict__ hn0)
{
    __shared__ float red[8];
    const int z0 = blockIdx.x * 2;
    const int c = threadIdx.x;
    const int lane = c & 63, w = c >> 6;

    float hv[2][16];
    #pragma unroll
    for (int zz = 0; zz < 2; ++zz)
        #pragma unroll
        for (int i = 0; i < 16; ++i)
            hv[zz][i] = bf2f(hbuf[((size_t)(z0 + zz) * DIRR + i) * COUT + c]);

    float s0 = wave_sum(hv[0][0]);
    float s1 = wave_sum(hv[1][0]);
    if (lane == 0) { red[w] = s0; red[4 + w] = s1; }
    __syncthreads();
    float m0 = (red[0] + red[1] + red[2] + red[3]) * (1.f / 256.f);
    float m1 = (red[4] + red[5] + red[6] + red[7]) * (1.f / 256.f);
    hv[0][0] -= m0;
    hv[1][0] -= m1;

    const float bal[4] = {0.25f, 1.f / 12.f, 1.f / 20.f, 1.f / 28.f};
    float var[2];
    #pragma unroll
    for (int zz = 0; zz < 2; ++zz) {
        float v = bal[0] * hv[zz][0] * hv[zz][0];
        #pragma unroll
        for (int i = 1; i < 16; ++i) {
            int li = (i < 4) ? 1 : (i < 9) ? 2 : 3;
            v += bal[li] * hv[zz][i] * hv[zz][i];
        }
        var[zz] = v;
    }
    float v0 = wave_sum(var[0]);
    float v1 = wave_sum(var[1]);
    __syncthreads();
    if (lane == 0) { red[w] = v0; red[4 + w] = v1; }
    __syncthreads();
    float inv[2];
    inv[0] = rsqrtf((red[0] + red[1] + red[2] + red[3]) * (1.f / 256.f) + 1e-5f);
    inv[1] = rsqrtf((red[4] + red[5] + red[6] + red[7]) * (1.f / 256.f) + 1e-5f);

    float a0 = afw[c], a1 = afw[COUT + c], a2 = afw[2 * COUT + c], a3 = afw[3 * COUT + c];
    #pragma unroll
    for (int zz = 0; zz < 2; ++zz) {
        s16x8 o0, o1;
        #pragma unroll
        for (int i = 0; i < 16; ++i) {
            float al = (i == 0) ? a0 : (i < 4) ? a1 : (i < 9) ? a2 : a3;
            ushort ub = f2bf(hv[zz][i] * inv[zz] * al);
            if (i < 8) o0[i] = (short)ub; else o1[i - 8] = (short)ub;
        }
        ushort* dst = hn2 + ((size_t)c * ZTOT + z0 + zz) * DIRR;
        *(s16x8*)dst = o0;
        *(s16x8*)(dst + 8) = o1;
        hn0[(size_t)(z0 + zz) * COUT + c] = (ushort)(unsigned short)o0[0];
    }
}

// ---------------------------------------------------------------------------
// K2b: gate GEMM — gate[z,c] = silu(hn0[z,:] @ gwb[c,:] + gb[c]) -> out i=0.
// ---------------------------------------------------------------------------
__global__ __launch_bounds__(256) void gate_k(const ushort* __restrict__ hn0,
                                              const ushort* __restrict__ gwb,
                                              const float* __restrict__ gb,
                                              float* __restrict__ out)
{
    const int b = blockIdx.x;
    const int tid = threadIdx.x;
    const int lane = tid & 63, w = tid >> 6;
    const int lr = lane & 15, kb = lane >> 4;

    f32x4 acc[4][4];
    #pragma unroll
    for (int m = 0; m < 4; ++m)
        #pragma unroll
        for (int n = 0; n < 4; ++n) acc[m][n] = (f32x4){0.f, 0.f, 0.f, 0.f};

    #pragma unroll 1
    for (int ks = 0; ks < 8; ++ks) {
        s16x8 av[4], bv[4];
        #pragma unroll
        for (int m = 0; m < 4; ++m)
            av[m] = *(const s16x8*)(hn0 + ((size_t)(b * 64 + m * 16 + lr) * 256 + ks * 32 + kb * 8));
        #pragma unroll
        for (int n = 0; n < 4; ++n)
            bv[n] = *(const s16x8*)(gwb + ((size_t)(w * 64 + n * 16 + lr) * 256 + ks * 32 + kb * 8));
        #pragma unroll
        for (int m = 0; m < 4; ++m)
            #pragma unroll
            for (int n = 0; n < 4; ++n)
                acc[m][n] = __builtin_amdgcn_mfma_f32_16x16x32_bf16(av[m], bv[n], acc[m][n], 0, 0, 0);
    }

    #pragma unroll
    for (int n = 0; n < 4; ++n) {
        int c = w * 64 + n * 16 + lr;
        float gbc = gb[c];
        #pragma unroll
        for (int m = 0; m < 4; ++m)
            #pragma unroll
            for (int r = 0; r < 4; ++r) {
                int nrow = m * 16 + kb * 4 + r;
                out[((size_t)b * COUT + c) * (DIRR * NN) + nrow] = silu(acc[m][n][r] + gbc);
            }
    }
}

// ---------------------------------------------------------------------------
// K2c: grid einsums batched over c. Block = (c, 256-z tile), 4 waves.
// ---------------------------------------------------------------------------
__global__ __launch_bounds__(256) void grid_k(const ushort* __restrict__ hn2,
                                              const ushort* __restrict__ tgb,
                                              const ushort* __restrict__ fgTb,
                                              float* __restrict__ out)
{
    __shared__ __align__(16) char lds[36864 + 2048 + 2304];
    ushort* P_s  = (ushort*)lds;                    // [256][72] bf16
    float*  S_s  = (float*)lds;                     // [256][17] f32 (aliases P_s)
    ushort* tg_s = (ushort*)(lds + 36864);          // [64][16]
    ushort* fgT_s= (ushort*)(lds + 36864 + 2048);   // [16][72]

    const int bid = blockIdx.x;
    const int c  = bid & 255;
    const int zt = bid >> 8;
    const int z0 = zt * 256;
    const int tid = threadIdx.x;
    const int lane = tid & 63, w = tid >> 6;
    const int lr = lane & 15, kb = lane >> 4;

    #pragma unroll
    for (int q = 0; q < 4; ++q) {
        int idx = q * 256 + tid;            // 1024
        tg_s[idx] = tgb[idx];
        int i = idx >> 6, p = idx & 63;
        fgT_s[i * 72 + p] = fgTb[idx];
    }
    __syncthreads();

    // ---- GEMM1 ----
    f32x4 acc[4][4];
    #pragma unroll
    for (int m = 0; m < 4; ++m)
        #pragma unroll
        for (int n = 0; n < 4; ++n) acc[m][n] = (f32x4){0.f, 0.f, 0.f, 0.f};

    s16x8 bv[4];
    #pragma unroll
    for (int n = 0; n < 4; ++n)
        bv[n] = (kb < 2) ? *(const s16x8*)(tg_s + (n * 16 + lr) * 16 + kb * 8)
                         : (s16x8){0,0,0,0,0,0,0,0};
    #pragma unroll
    for (int m = 0; m < 4; ++m) {
        int zl = w * 64 + m * 16 + lr;
        s16x8 av = (kb < 2) ? *(const s16x8*)(hn2 + ((size_t)c * ZTOT + z0 + zl) * DIRR + kb * 8)
                            : (s16x8){0,0,0,0,0,0,0,0};
        #pragma unroll
        for (int n = 0; n < 4; ++n)
            acc[m][n] = __builtin_amdgcn_mfma_f32_16x16x32_bf16(av, bv[n], acc[m][n], 0, 0, 0);
    }

    // ---- silu -> P_s (wave-local region) ----
    #pragma unroll
    for (int m = 0; m < 4; ++m)
        #pragma unroll
        for (int n = 0; n < 4; ++n)
            #pragma unroll
            for (int r = 0; r < 4; ++r) {
                int zl = w * 64 + m * 16 + kb * 4 + r;
                int p  = n * 16 + lr;
                P_s[zl * 72 + p] = f2bf(silu(acc[m][n][r]));
            }

    // ---- GEMM2 (reads only this wave's P_s rows; in-wave DS ordering) ----
    f32x4 acc2[4];
    #pragma unroll
    for (int m = 0; m < 4; ++m) acc2[m] = (f32x4){0.f, 0.f, 0.f, 0.f};
    #pragma unroll
    for (int ks = 0; ks < 2; ++ks) {
        s16x8 bv2 = *(const s16x8*)(fgT_s + lr * 72 + ks * 32 + kb * 8);
        #pragma unroll
        for (int m = 0; m < 4; ++m) {
            s16x8 av2 = *(const s16x8*)(P_s + (w * 64 + m * 16 + lr) * 72 + ks * 32 + kb * 8);
            acc2[m] = __builtin_amdgcn_mfma_f32_16x16x32_bf16(av2, bv2, acc2[m], 0, 0, 0);
        }
    }

    __syncthreads();        // all waves done with P_s before S_s overwrites it

    #pragma unroll
    for (int m = 0; m < 4; ++m)
        #pragma unroll
        for (int r = 0; r < 4; ++r) {
            int zl = w * 64 + m * 16 + kb * 4 + r;
            S_s[zl * 17 + lr] = acc2[m][r];
        }
    __syncthreads();

    // ---- coalesced output: i = 1..15 ----
    const int bb = tid >> 6, n = tid & 63;
    const int b0 = zt * 4;
    const float* srow = S_s + (bb * 64 + n) * 17;
    float* obase = out + ((size_t)(b0 + bb) * COUT + c) * (DIRR * NN) + n;
    #pragma unroll
    for (int i = 1; i < 16; ++i)
        obase[i * NN] = srow[i];
}

// ---------------------------------------------------------------------------
// Fallback K2 (round-2 proven) if ws_size is too small for the split path.
// ---------------------------------------------------------------------------
__global__ __launch_bounds__(256) void post_k(const ushort* __restrict__ hbuf,
                                              const float* __restrict__ afw,
                                              const float* __restrict__ gw,
                                              const float* __restrict__ gb,
                                              const float* __restrict__ tg,
                                              const float* __restrict__ fg,
                                              float* __restrict__ out)
{
    __shared__ float h0s[COUT];
    __shared__ float red[4];
    __shared__ float tgs[64 * 16];
    __shared__ float fgs[64 * 16];

    int z = blockIdx.x;
    int c = threadIdx.x;
    int b = z >> 6, n = z & 63;
    int lane = c & 63, wid = c >> 6;

    for (int idx = c; idx < 1024; idx += 256) { tgs[idx] = tg[idx]; fgs[idx] = fg[idx]; }

    float hv[16];
    #pragma unroll
    for (int i = 0; i < 16; ++i)
        hv[i] = bf2f(hbuf[((size_t)z * DIRR + i) * COUT + c]);

    float s0 = wave_sum(hv[0]);
    if (lane == 0) red[wid] = s0;
    __syncthreads();
    float mean0 = (red[0] + red[1] + red[2] + red[3]) * (1.f / 256.f);
    hv[0] -= mean0;

    const float bal[4] = {0.25f, 1.f / 12.f, 1.f / 20.f, 1.f / 28.f};
    float var = bal[0] * hv[0] * hv[0];
    #pragma unroll
    for (int i = 1; i < 16; ++i) {
        int li = (i < 4) ? 1 : (i < 9) ? 2 : 3;
        var += bal[li] * hv[i] * hv[i];
    }
    float s1 = wave_sum(var);
    __syncthreads();
    if (lane == 0) red[wid] = s1;
    __syncthreads();
    float inv = rsqrtf((red[0] + red[1] + red[2] + red[3]) * (1.f / 256.f) + 1e-5f);

    float a0 = afw[c], a1 = afw[COUT + c], a2 = afw[2 * COUT + c], a3 = afw[3 * COUT + c];
    #pragma unroll
    for (int i = 0; i < 16; ++i) {
        float al = (i == 0) ? a0 : (i < 4) ? a1 : (i < 9) ? a2 : a3;
        hv[i] *= inv * al;
    }
    h0s[c] = hv[0];
    __syncthreads();

    float g = gb[c];
    const float4* gwr = (const float4*)(gw + (size_t)c * COUT);
    #pragma unroll 4
    for (int j = 0; j < 64; ++j) {
        float4 wv = gwr[j];
        g += h0s[4 * j] * wv.x + h0s[4 * j + 1] * wv.y + h0s[4 * j + 2] * wv.z + h0s[4 * j + 3] * wv.w;
    }
    float gate = silu(g);

    float s2a[16];
    #pragma unroll
    for (int i = 0; i < 16; ++i) s2a[i] = 0.f;
    #pragma unroll 1
    for (int p = 0; p < 64; ++p) {
        float gv = 0.f;
        #pragma unroll
        for (int i = 0; i < 16; ++i) gv += tgs[p * 16 + i] * hv[i];
        gv = silu(gv);
        #pragma unroll
        for (int i = 0; i < 16; ++i) s2a[i] += fgs[p * 16 + i] * gv;
    }

    float* ob = out + (size_t)b * COUT * DIRR * NN + (size_t)c * DIRR * NN + n;
    ob[0] = gate;
    #pragma unroll
    for (int i = 1; i < 16; ++i) ob[i * NN] = s2a[i];
}

extern "C" void kernel_launch(void* const* d_in, const int* in_sizes, int n_in,
                              void* d_out, int out_size, void* d_ws, size_t ws_size,
                              hipStream_t stream)
{
    const float* x    = (const float*)d_in[0];
    const float* w    = (const float*)d_in[1];
    const float* bias = (const float*)d_in[2];
    const float* afw  = (const float*)d_in[3];
    const float* gw   = (const float*)d_in[4];
    const float* gb   = (const float*)d_in[5];
    const float* tg   = (const float*)d_in[6];
    const float* fg   = (const float*)d_in[7];
    float* out = (float*)d_out;

    const size_t off_hbuf = 0;                         // 64 MiB
    const size_t off_wb   = 67108864;                  // 2.62 MiB
    const size_t off_hn2  = 69730304;                  // 64 MiB
    const size_t off_hn0  = off_hn2 + 67108864;        // 4 MiB
    const size_t off_gwb  = off_hn0 + 4194304;         // 128 KiB
    const size_t off_tgb  = off_gwb + 131072;          // 2 KiB
    const size_t off_fgT  = off_tgb + 2048;            // 2 KiB
    const size_t need     = off_fgT + 2048;            // ~134.6 MiB

    ushort* hbuf = (ushort*)((char*)d_ws + off_hbuf);
    ushort* wb   = (ushort*)((char*)d_ws + off_wb);

    pack_w_k   <<<5120, 256, 0, stream>>>(w, wb);
    conv_mfma_k<<<BB * DIRR, 256, 0, stream>>>(x, wb, bias, hbuf);

    if (ws_size >= need) {
        ushort* hn2  = (ushort*)((char*)d_ws + off_hn2);
        ushort* hn0  = (ushort*)((char*)d_ws + off_hn0);
        ushort* gwb  = (ushort*)((char*)d_ws + off_gwb);
        ushort* tgb  = (ushort*)((char*)d_ws + off_tgb);
        ushort* fgTb = (ushort*)((char*)d_ws + off_fgT);

        pack2_k<<<264, 256, 0, stream>>>(gw, tg, fg, gwb, tgb, fgTb);
        norm_k <<<ZTOT / 2, 256, 0, stream>>>(hbuf, afw, hn2, hn0);
        gate_k <<<BB, 256, 0, stream>>>(hn0, gwb, gb, out);
        grid_k <<<256 * (ZTOT / 256), 256, 0, stream>>>(hn2, tgb, fgTb, out);
    } else {
        post_k<<<ZTOT, 256, 0, stream>>>(hbuf, afw, gw, gb, tg, fg, out);
    }
}

// Round 7
// 255.587 us; speedup vs baseline: 1.1091x; 1.1091x over previous
//
#include <hip/hip_runtime.h>
#include <hip/hip_bf16.h>

#define BB    128
#define CIN   256
#define COUT  256
#define NN    64
#define KW    5
#define DIRR  16
#define ZTOT  (BB*NN)
#define SX    264   // xs row stride (bf16): 528 B = 33*16 -> odd 16B-slot stride, A-reads conflict-free

typedef __attribute__((ext_vector_type(4))) float f32x4;
typedef __attribute__((ext_vector_type(8))) short s16x8;

__device__ inline ushort f2bf(float f) {
    __hip_bfloat16 h = __float2bfloat16(f);
    return *(const ushort*)&h;
}
__device__ inline float bf2f(ushort u) {
    union { unsigned int ui; float f; } cv; cv.ui = ((unsigned int)u) << 16;
    return cv.f;
}
__device__ inline float wave_sum(float v) {
    #pragma unroll
    for (int o = 32; o > 0; o >>= 1) v += __shfl_down(v, o, 64);
    return v;
}
__device__ inline float silu(float x) { return x / (1.f + __expf(-x)); }

// ---------------------------------------------------------------------------
// K0a: pack conv weights f32 -> bf16, LINEAR layout wb[l][k][chunk8][c256][cin32]
// (B-frags are consumed directly from L2 by exactly one lane each — no LDS.)
// ---------------------------------------------------------------------------
__global__ __launch_bounds__(256) void pack_w_k(const float* __restrict__ w,
                                                ushort* __restrict__ wb)
{
    int idx = blockIdx.x * 256 + threadIdx.x;      // 1310720
    int cl = idx & 31;
    int c  = (idx >> 5) & 255;
    int ch = (idx >> 13) & 7;
    int k  = (idx >> 16) % 5;
    int l  = idx / 327680;
    int cin = ch * 32 + cl;
    wb[idx] = f2bf(w[(((size_t)(l * COUT + c) * CIN) + cin) * KW + k]);
}

// ---------------------------------------------------------------------------
// K0b: pack gw (bf16 [c][k]), tg (bf16 [p][i]), fg transposed (bf16 [i][p])
// ---------------------------------------------------------------------------
__global__ __launch_bounds__(256) void pack2_k(const float* __restrict__ gw,
                                               const float* __restrict__ tg,
                                               const float* __restrict__ fg,
                                               ushort* __restrict__ gwb,
                                               ushort* __restrict__ tgb,
                                               ushort* __restrict__ fgTb)
{
    int idx = blockIdx.x * 256 + threadIdx.x;      // 67584 total
    if (idx < 65536) {
        gwb[idx] = f2bf(gw[idx]);
    } else if (idx < 66560) {
        int j = idx - 65536;
        tgb[j] = f2bf(tg[j]);
    } else if (idx < 67584) {
        int j = idx - 66560;                        // j = p*16 + i
        int p = j >> 4, i = j & 15;
        fgTb[i * 64 + p] = f2bf(fg[j]);
    }
}

// ---------------------------------------------------------------------------
// K1: per-(b,i) conv as bf16 MFMA GEMM. M=64(n) x N=256(c), K=5 shifts x 256 cin.
// A (x-tile) in LDS, shared by all waves. B (weights) loaded DIRECTLY from
// global (L2-hot, each frag consumed by exactly one lane) — no bs LDS buffer,
// no K-loop barriers, 36 KB LDS -> 4 blocks/CU.
// ---------------------------------------------------------------------------
__global__ __launch_bounds__(256) void conv_mfma_k(const float* __restrict__ x,
                                                   const ushort* __restrict__ wb,
                                                   const float* __restrict__ bias,
                                                   ushort* __restrict__ hbuf)
{
    __shared__ __align__(16) ushort xs[68 * SX];        // [n+2halo][cin]  ~35.9 KB

    const int tid  = threadIdx.x;
    const int lane = tid & 63;
    const int wid  = tid >> 6;
    const int blk  = blockIdx.x;
    const int b = blk >> 4, i = blk & 15;
    const int l = (i == 0) ? 0 : (i < 4) ? 1 : (i < 9) ? 2 : 3;

    // ---- stage x[b,:,i,:] transposed -> xs[2+n][cin], cin-major lanes:
    // 64 consecutive cin per row => 128 B contiguous b16 stores, conflict-free
    {
        const float4* xb = (const float4*)(x + (((size_t)b * CIN) * DIRR + i) * NN);
        #pragma unroll
        for (int p = 0; p < 16; ++p) {
            int cin = (tid & 63) | ((p & 3) << 6);      // 0..255
            int nq  = ((tid >> 6) << 2) | (p >> 2);     // 0..15 (float4 index in n)
            float4 v = xb[(size_t)cin * (DIRR * NN / 4) + nq];
            ushort* dst = xs + (size_t)(2 + nq * 4) * SX + cin;
            dst[0]      = f2bf(v.x);
            dst[SX]     = f2bf(v.y);
            dst[2 * SX] = f2bf(v.z);
            dst[3 * SX] = f2bf(v.w);
        }
        xs[ 0 * SX + tid] = 0; xs[ 1 * SX + tid] = 0;
        xs[66 * SX + tid] = 0; xs[67 * SX + tid] = 0;
    }
    __syncthreads();                                    // the ONLY barrier

    f32x4 acc[4][4];
    #pragma unroll
    for (int m = 0; m < 4; ++m)
        #pragma unroll
        for (int j = 0; j < 4; ++j) acc[m][j] = (f32x4){0.f, 0.f, 0.f, 0.f};

    const int kb = lane >> 4;
    const int lr = lane & 15;

    // B-frag global element offsets within a (s,ch) tile: c*32 + kb*8
    const ushort* wl = wb + (size_t)l * (5 * 8 * 8192);
    int boffB[4];
    #pragma unroll
    for (int j = 0; j < 4; ++j)
        boffB[j] = (wid * 64 + j * 16 + lr) * 32 + kb * 8;

    // A row base (element offset in xs): row m*16+lr, col kb*8; + s*SX + ch*32 at use
    const ushort* arow[4];
    #pragma unroll
    for (int m = 0; m < 4; ++m)
        arow[m] = xs + (size_t)(m * 16 + lr) * SX + kb * 8;

    #pragma unroll 1
    for (int s = 0; s < 5; ++s) {
        const ushort* bt_s = wl + (size_t)s * 8 * 8192;
        const ushort* ar_s0 = arow[0] + s * SX;
        const ushort* ar_s1 = arow[1] + s * SX;
        const ushort* ar_s2 = arow[2] + s * SX;
        const ushort* ar_s3 = arow[3] + s * SX;
        #pragma unroll 2
        for (int ch = 0; ch < 8; ++ch) {
            const ushort* bt = bt_s + ch * 8192;
            s16x8 bv[4], av[4];
            #pragma unroll
            for (int j = 0; j < 4; ++j)
                bv[j] = *(const s16x8*)(bt + boffB[j]);
            av[0] = *(const s16x8*)(ar_s0 + ch * 32);
            av[1] = *(const s16x8*)(ar_s1 + ch * 32);
            av[2] = *(const s16x8*)(ar_s2 + ch * 32);
            av[3] = *(const s16x8*)(ar_s3 + ch * 32);
            #pragma unroll
            for (int m = 0; m < 4; ++m)
                #pragma unroll
                for (int j = 0; j < 4; ++j)
                    acc[m][j] = __builtin_amdgcn_mfma_f32_16x16x32_bf16(av[m], bv[j], acc[m][j], 0, 0, 0);
        }
    }

    // ---- epilogue: bias (i==0) + bf16 store. D: col=lane&15, row=(lane>>4)*4+r
    const int row0 = (lane >> 4) * 4;
    #pragma unroll
    for (int j = 0; j < 4; ++j) {
        int c = wid * 64 + j * 16 + lr;
        float bvv = (i == 0) ? bias[c] : 0.f;
        #pragma unroll
        for (int m = 0; m < 4; ++m)
            #pragma unroll
            for (int r = 0; r < 4; ++r) {
                int n = m * 16 + row0 + r;
                size_t z = (size_t)b * NN + n;
                hbuf[(z * DIRR + i) * COUT + c] = f2bf(acc[m][j][r] + bvv);
            }
    }
}

// ---------------------------------------------------------------------------
// K2a: norm per z (block = 2 z). Writes hn2[c][z][i] bf16 + hn0[z][c] bf16.
// ---------------------------------------------------------------------------
__global__ __launch_bounds__(256) void norm_k(const ushort* __restrict__ hbuf,
                                              const float* __restrict__ afw,
                                              ushort* __restrict__ hn2,
                                              ushort* __restrict__ hn0)
{
    __shared__ float red[8];
    const int z0 = blockIdx.x * 2;
    const int c = threadIdx.x;
    const int lane = c & 63, w = c >> 6;

    float hv[2][16];
    #pragma unroll
    for (int zz = 0; zz < 2; ++zz)
        #pragma unroll
        for (int i = 0; i < 16; ++i)
            hv[zz][i] = bf2f(hbuf[((size_t)(z0 + zz) * DIRR + i) * COUT + c]);

    float s0 = wave_sum(hv[0][0]);
    float s1 = wave_sum(hv[1][0]);
    if (lane == 0) { red[w] = s0; red[4 + w] = s1; }
    __syncthreads();
    float m0 = (red[0] + red[1] + red[2] + red[3]) * (1.f / 256.f);
    float m1 = (red[4] + red[5] + red[6] + red[7]) * (1.f / 256.f);
    hv[0][0] -= m0;
    hv[1][0] -= m1;

    const float bal[4] = {0.25f, 1.f / 12.f, 1.f / 20.f, 1.f / 28.f};
    float var[2];
    #pragma unroll
    for (int zz = 0; zz < 2; ++zz) {
        float v = bal[0] * hv[zz][0] * hv[zz][0];
        #pragma unroll
        for (int i = 1; i < 16; ++i) {
            int li = (i < 4) ? 1 : (i < 9) ? 2 : 3;
            v += bal[li] * hv[zz][i] * hv[zz][i];
        }
        var[zz] = v;
    }
    float v0 = wave_sum(var[0]);
    float v1 = wave_sum(var[1]);
    __syncthreads();
    if (lane == 0) { red[w] = v0; red[4 + w] = v1; }
    __syncthreads();
    float inv[2];
    inv[0] = rsqrtf((red[0] + red[1] + red[2] + red[3]) * (1.f / 256.f) + 1e-5f);
    inv[1] = rsqrtf((red[4] + red[5] + red[6] + red[7]) * (1.f / 256.f) + 1e-5f);

    float a0 = afw[c], a1 = afw[COUT + c], a2 = afw[2 * COUT + c], a3 = afw[3 * COUT + c];
    #pragma unroll
    for (int zz = 0; zz < 2; ++zz) {
        s16x8 o0, o1;
        #pragma unroll
        for (int i = 0; i < 16; ++i) {
            float al = (i == 0) ? a0 : (i < 4) ? a1 : (i < 9) ? a2 : a3;
            ushort ub = f2bf(hv[zz][i] * inv[zz] * al);
            if (i < 8) o0[i] = (short)ub; else o1[i - 8] = (short)ub;
        }
        ushort* dst = hn2 + ((size_t)c * ZTOT + z0 + zz) * DIRR;
        *(s16x8*)dst = o0;
        *(s16x8*)(dst + 8) = o1;
        hn0[(size_t)(z0 + zz) * COUT + c] = (ushort)(unsigned short)o0[0];
    }
}

// ---------------------------------------------------------------------------
// K2b: gate GEMM — gate[z,c] = silu(hn0[z,:] @ gwb[c,:] + gb[c]) -> out i=0.
// ---------------------------------------------------------------------------
__global__ __launch_bounds__(256) void gate_k(const ushort* __restrict__ hn0,
                                              const ushort* __restrict__ gwb,
                                              const float* __restrict__ gb,
                                              float* __restrict__ out)
{
    const int b = blockIdx.x;
    const int tid = threadIdx.x;
    const int lane = tid & 63, w = tid >> 6;
    const int lr = lane & 15, kb = lane >> 4;

    f32x4 acc[4][4];
    #pragma unroll
    for (int m = 0; m < 4; ++m)
        #pragma unroll
        for (int n = 0; n < 4; ++n) acc[m][n] = (f32x4){0.f, 0.f, 0.f, 0.f};

    #pragma unroll 1
    for (int ks = 0; ks < 8; ++ks) {
        s16x8 av[4], bv[4];
        #pragma unroll
        for (int m = 0; m < 4; ++m)
            av[m] = *(const s16x8*)(hn0 + ((size_t)(b * 64 + m * 16 + lr) * 256 + ks * 32 + kb * 8));
        #pragma unroll
        for (int n = 0; n < 4; ++n)
            bv[n] = *(const s16x8*)(gwb + ((size_t)(w * 64 + n * 16 + lr) * 256 + ks * 32 + kb * 8));
        #pragma unroll
        for (int m = 0; m < 4; ++m)
            #pragma unroll
            for (int n = 0; n < 4; ++n)
                acc[m][n] = __builtin_amdgcn_mfma_f32_16x16x32_bf16(av[m], bv[n], acc[m][n], 0, 0, 0);
    }

    #pragma unroll
    for (int n = 0; n < 4; ++n) {
        int c = w * 64 + n * 16 + lr;
        float gbc = gb[c];
        #pragma unroll
        for (int m = 0; m < 4; ++m)
            #pragma unroll
            for (int r = 0; r < 4; ++r) {
                int nrow = m * 16 + kb * 4 + r;
                out[((size_t)b * COUT + c) * (DIRR * NN) + nrow] = silu(acc[m][n][r] + gbc);
            }
    }
}

// ---------------------------------------------------------------------------
// K2c: grid einsums batched over c. Block = (c, 256-z tile), 4 waves.
// ---------------------------------------------------------------------------
__global__ __launch_bounds__(256) void grid_k(const ushort* __restrict__ hn2,
                                              const ushort* __restrict__ tgb,
                                              const ushort* __restrict__ fgTb,
                                              float* __restrict__ out)
{
    __shared__ __align__(16) char lds[36864 + 2048 + 2304];
    ushort* P_s  = (ushort*)lds;                    // [256][72] bf16
    float*  S_s  = (float*)lds;                     // [256][17] f32 (aliases P_s)
    ushort* tg_s = (ushort*)(lds + 36864);          // [64][16]
    ushort* fgT_s= (ushort*)(lds + 36864 + 2048);   // [16][72]

    const int bid = blockIdx.x;
    const int c  = bid & 255;
    const int zt = bid >> 8;
    const int z0 = zt * 256;
    const int tid = threadIdx.x;
    const int lane = tid & 63, w = tid >> 6;
    const int lr = lane & 15, kb = lane >> 4;

    #pragma unroll
    for (int q = 0; q < 4; ++q) {
        int idx = q * 256 + tid;            // 1024
        tg_s[idx] = tgb[idx];
        int i = idx >> 6, p = idx & 63;
        fgT_s[i * 72 + p] = fgTb[idx];
    }
    __syncthreads();

    // ---- GEMM1 ----
    f32x4 acc[4][4];
    #pragma unroll
    for (int m = 0; m < 4; ++m)
        #pragma unroll
        for (int n = 0; n < 4; ++n) acc[m][n] = (f32x4){0.f, 0.f, 0.f, 0.f};

    s16x8 bv[4];
    #pragma unroll
    for (int n = 0; n < 4; ++n)
        bv[n] = (kb < 2) ? *(const s16x8*)(tg_s + (n * 16 + lr) * 16 + kb * 8)
                         : (s16x8){0,0,0,0,0,0,0,0};
    #pragma unroll
    for (int m = 0; m < 4; ++m) {
        int zl = w * 64 + m * 16 + lr;
        s16x8 av = (kb < 2) ? *(const s16x8*)(hn2 + ((size_t)c * ZTOT + z0 + zl) * DIRR + kb * 8)
                            : (s16x8){0,0,0,0,0,0,0,0};
        #pragma unroll
        for (int n = 0; n < 4; ++n)
            acc[m][n] = __builtin_amdgcn_mfma_f32_16x16x32_bf16(av, bv[n], acc[m][n], 0, 0, 0);
    }

    // ---- silu -> P_s (wave-local region) ----
    #pragma unroll
    for (int m = 0; m < 4; ++m)
        #pragma unroll
        for (int n = 0; n < 4; ++n)
            #pragma unroll
            for (int r = 0; r < 4; ++r) {
                int zl = w * 64 + m * 16 + kb * 4 + r;
                int p  = n * 16 + lr;
                P_s[zl * 72 + p] = f2bf(silu(acc[m][n][r]));
            }

    // ---- GEMM2 (reads only this wave's P_s rows; in-wave DS ordering) ----
    f32x4 acc2[4];
    #pragma unroll
    for (int m = 0; m < 4; ++m) acc2[m] = (f32x4){0.f, 0.f, 0.f, 0.f};
    #pragma unroll
    for (int ks = 0; ks < 2; ++ks) {
        s16x8 bv2 = *(const s16x8*)(fgT_s + lr * 72 + ks * 32 + kb * 8);
        #pragma unroll
        for (int m = 0; m < 4; ++m) {
            s16x8 av2 = *(const s16x8*)(P_s + (w * 64 + m * 16 + lr) * 72 + ks * 32 + kb * 8);
            acc2[m] = __builtin_amdgcn_mfma_f32_16x16x32_bf16(av2, bv2, acc2[m], 0, 0, 0);
        }
    }

    __syncthreads();        // all waves done with P_s before S_s overwrites it

    #pragma unroll
    for (int m = 0; m < 4; ++m)
        #pragma unroll
        for (int r = 0; r < 4; ++r) {
            int zl = w * 64 + m * 16 + kb * 4 + r;
            S_s[zl * 17 + lr] = acc2[m][r];
        }
    __syncthreads();

    // ---- coalesced output: i = 1..15 ----
    const int bb = tid >> 6, n = tid & 63;
    const int b0 = zt * 4;
    const float* srow = S_s + (bb * 64 + n) * 17;
    float* obase = out + ((size_t)(b0 + bb) * COUT + c) * (DIRR * NN) + n;
    #pragma unroll
    for (int i = 1; i < 16; ++i)
        obase[i * NN] = srow[i];
}

// ---------------------------------------------------------------------------
// Fallback K2 (round-2 proven) if ws_size is too small for the split path.
// ---------------------------------------------------------------------------
__global__ __launch_bounds__(256) void post_k(const ushort* __restrict__ hbuf,
                                              const float* __restrict__ afw,
                                              const float* __restrict__ gw,
                                              const float* __restrict__ gb,
                                              const float* __restrict__ tg,
                                              const float* __restrict__ fg,
                                              float* __restrict__ out)
{
    __shared__ float h0s[COUT];
    __shared__ float red[4];
    __shared__ float tgs[64 * 16];
    __shared__ float fgs[64 * 16];

    int z = blockIdx.x;
    int c = threadIdx.x;
    int b = z >> 6, n = z & 63;
    int lane = c & 63, wid = c >> 6;

    for (int idx = c; idx < 1024; idx += 256) { tgs[idx] = tg[idx]; fgs[idx] = fg[idx]; }

    float hv[16];
    #pragma unroll
    for (int i = 0; i < 16; ++i)
        hv[i] = bf2f(hbuf[((size_t)z * DIRR + i) * COUT + c]);

    float s0 = wave_sum(hv[0]);
    if (lane == 0) red[wid] = s0;
    __syncthreads();
    float mean0 = (red[0] + red[1] + red[2] + red[3]) * (1.f / 256.f);
    hv[0] -= mean0;

    const float bal[4] = {0.25f, 1.f / 12.f, 1.f / 20.f, 1.f / 28.f};
    float var = bal[0] * hv[0] * hv[0];
    #pragma unroll
    for (int i = 1; i < 16; ++i) {
        int li = (i < 4) ? 1 : (i < 9) ? 2 : 3;
        var += bal[li] * hv[i] * hv[i];
    }
    float s1 = wave_sum(var);
    __syncthreads();
    if (lane == 0) red[wid] = s1;
    __syncthreads();
    float inv = rsqrtf((red[0] + red[1] + red[2] + red[3]) * (1.f / 256.f) + 1e-5f);

    float a0 = afw[c], a1 = afw[COUT + c], a2 = afw[2 * COUT + c], a3 = afw[3 * COUT + c];
    #pragma unroll
    for (int i = 0; i < 16; ++i) {
        float al = (i == 0) ? a0 : (i < 4) ? a1 : (i < 9) ? a2 : a3;
        hv[i] *= inv * al;
    }
    h0s[c] = hv[0];
    __syncthreads();

    float g = gb[c];
    const float4* gwr = (const float4*)(gw + (size_t)c * COUT);
    #pragma unroll 4
    for (int j = 0; j < 64; ++j) {
        float4 wv = gwr[j];
        g += h0s[4 * j] * wv.x + h0s[4 * j + 1] * wv.y + h0s[4 * j + 2] * wv.z + h0s[4 * j + 3] * wv.w;
    }
    float gate = silu(g);

    float s2a[16];
    #pragma unroll
    for (int i = 0; i < 16; ++i) s2a[i] = 0.f;
    #pragma unroll 1
    for (int p = 0; p < 64; ++p) {
        float gv = 0.f;
        #pragma unroll
        for (int i = 0; i < 16; ++i) gv += tgs[p * 16 + i] * hv[i];
        gv = silu(gv);
        #pragma unroll
        for (int i = 0; i < 16; ++i) s2a[i] += fgs[p * 16 + i] * gv;
    }

    float* ob = out + (size_t)b * COUT * DIRR * NN + (size_t)c * DIRR * NN + n;
    ob[0] = gate;
    #pragma unroll
    for (int i = 1; i < 16; ++i) ob[i * NN] = s2a[i];
}

extern "C" void kernel_launch(void* const* d_in, const int* in_sizes, int n_in,
                              void* d_out, int out_size, void* d_ws, size_t ws_size,
                              hipStream_t stream)
{
    const float* x    = (const float*)d_in[0];
    const float* w    = (const float*)d_in[1];
    const float* bias = (const float*)d_in[2];
    const float* afw  = (const float*)d_in[3];
    const float* gw   = (const float*)d_in[4];
    const float* gb   = (const float*)d_in[5];
    const float* tg   = (const float*)d_in[6];
    const float* fg   = (const float*)d_in[7];
    float* out = (float*)d_out;

    const size_t off_hbuf = 0;                         // 64 MiB
    const size_t off_wb   = 67108864;                  // 2.62 MiB
    const size_t off_hn2  = 69730304;                  // 64 MiB
    const size_t off_hn0  = off_hn2 + 67108864;        // 4 MiB
    const size_t off_gwb  = off_hn0 + 4194304;         // 128 KiB
    const size_t off_tgb  = off_gwb + 131072;          // 2 KiB
    const size_t off_fgT  = off_tgb + 2048;            // 2 KiB
    const size_t need     = off_fgT + 2048;            // ~134.6 MiB

    ushort* hbuf = (ushort*)((char*)d_ws + off_hbuf);
    ushort* wb   = (ushort*)((char*)d_ws + off_wb);

    pack_w_k   <<<5120, 256, 0, stream>>>(w, wb);
    conv_mfma_k<<<BB * DIRR, 256, 0, stream>>>(x, wb, bias, hbuf);

    if (ws_size >= need) {
        ushort* hn2  = (ushort*)((char*)d_ws + off_hn2);
        ushort* hn0  = (ushort*)((char*)d_ws + off_hn0);
        ushort* gwb  = (ushort*)((char*)d_ws + off_gwb);
        ushort* tgb  = (ushort*)((char*)d_ws + off_tgb);
        ushort* fgTb = (ushort*)((char*)d_ws + off_fgT);

        pack2_k<<<264, 256, 0, stream>>>(gw, tg, fg, gwb, tgb, fgTb);
        norm_k <<<ZTOT / 2, 256, 0, stream>>>(hbuf, afw, hn2, hn0);
        gate_k <<<BB, 256, 0, stream>>>(hn0, gwb, gb, out);
        grid_k <<<256 * (ZTOT / 256), 256, 0, stream>>>(hn2, tgb, fgTb, out);
    } else {
        post_k<<<ZTOT, 256, 0, stream>>>(hbuf, afw, gw, gb, tg, fg, out);
    }
}